// Round 1
// 379.124 us; speedup vs baseline: 1.0276x; 1.0276x over previous
//
#include <hip/hip_runtime.h>
#include <stdint.h>

#define HH 1024
#define WW 2048
#define HWN (HH*WW)          // 2097152
#define BIGL HWN             // 'no cluster' sentinel
#define NSLOTS 26
#define MINCL 30
#define THREADS 256
#define LTHREADS 512         // k_local block size (8 waves)
#define MAXCAND 70000        // >= HWN/30 + 1
#define HSZ 512              // run-aggregation hash entries (256-pixel strip)
#define TILE 4096            // 64x64 tile
#define NTILES 512           // (1024/64)*(2048/64)
#define NB 128               // selection blocks

typedef int vi4 __attribute__((ext_vector_type(4)));
typedef unsigned long long u64;

// ---------------- global union-find (lock-free, min-root) ----------------
__device__ __forceinline__ int uf_load(int* p, int i) {
    return __hip_atomic_load(&p[i], __ATOMIC_RELAXED, __HIP_MEMORY_SCOPE_AGENT);
}
__device__ __forceinline__ void uf_store(int* p, int i, int v) {
    __hip_atomic_store(&p[i], v, __ATOMIC_RELAXED, __HIP_MEMORY_SCOPE_AGENT);
}
__device__ int uf_find(int* parent, int x) {
    int p = uf_load(parent, x);
    while (p != x) {
        int gp = uf_load(parent, p);
        if (gp != p) uf_store(parent, x, gp);   // path halving (benign race)
        x = p; p = gp;
    }
    return p;
}
__device__ void uf_union(int* parent, int a, int b) {
    int ra = uf_find(parent, a);
    int rb = uf_find(parent, b);
    while (ra != rb) {
        if (ra > rb) { int t = ra; ra = rb; rb = t; }   // hook larger under smaller
        int old = atomicCAS(&parent[rb], rb, ra);
        if (old == rb) return;
        rb = uf_find(parent, old);
        ra = uf_find(parent, ra);
    }
}

// ---------------- LDS union-find (block-local, min-root) ----------------
__device__ __forceinline__ int l_load(int* p, int i) {
    return __hip_atomic_load(&p[i], __ATOMIC_RELAXED, __HIP_MEMORY_SCOPE_WORKGROUP);
}
__device__ __forceinline__ void l_store(int* p, int i, int v) {
    __hip_atomic_store(&p[i], v, __ATOMIC_RELAXED, __HIP_MEMORY_SCOPE_WORKGROUP);
}
__device__ int l_find(int* lp, int x) {
    int p = l_load(lp, x);
    while (p != x) {
        int gp = l_load(lp, p);
        if (gp != p) l_store(lp, x, gp);
        x = p; p = gp;
    }
    return p;
}
__device__ void l_union(int* lp, int a, int b) {
    int ra = l_find(lp, a);
    int rb = l_find(lp, b);
    while (ra != rb) {
        if (ra > rb) { int t = ra; ra = rb; rb = t; }
        int old = atomicCAS(&lp[rb], rb, ra);
        if (old == rb) return;
        rb = l_find(lp, old);
        ra = l_find(lp, ra);
    }
}

// ---------------- fused init + per-tile CC + ws zeroing ----------------
// parent[] is self-describing: -1 for non-core, global tile-root for core.
__global__ __launch_bounds__(LTHREADS) void k_local(const float* __restrict__ mask,
                                                    uint8_t* __restrict__ flags,
                                                    int* __restrict__ parent,
                                                    int* __restrict__ sizes,
                                                    unsigned* __restrict__ colsum,
                                                    signed char* __restrict__ chan,
                                                    int* __restrict__ counter) {
    __shared__ uint8_t lact[66 * 72];   // halo active map, row stride 72
    __shared__ uint8_t lc8[TILE];
    __shared__ int lp[TILE];
    const int tid = threadIdx.x;
    int tile_x = blockIdx.x & 31, tile_y = blockIdx.x >> 5;
    int r0 = tile_y << 6, c0 = tile_x << 6;

    {   // zero this block's 1/512 slice of sizes/colsum/chan (+counter/done once)
        int base = blockIdx.x * (HWN / NTILES);      // 4096 elements
        vi4* sz4 = (vi4*)(sizes + base);
        vi4* cs4 = (vi4*)(colsum + base);
        for (int t = tid; t < 1024; t += LTHREADS) sz4[t] = (vi4)0;
        for (int t = tid; t < 1024; t += LTHREADS) cs4[t] = (vi4)0;   // u32 colsum
        vi4* ch4 = (vi4*)(chan + base);
        for (int t = tid; t < 256; t += LTHREADS) ch4[t] = (vi4)(-1);
        if (blockIdx.x == 0 && tid == 0) { counter[0] = 0; counter[1] = 0; }
    }

    {   // body rows: 64 rows x 16 float4, coalesced; 512 threads -> 2 passes
        int lr = tid >> 4, q = tid & 15;
        #pragma unroll
        for (int pass = 0; pass < 2; ++pass) {
            int rr = lr + pass * 32;
            const float4* src = (const float4*)(mask + (size_t)(r0 + rr) * WW + c0);
            float4 v = src[q];
            uint8_t* dst = &lact[(rr + 1) * 72 + (q * 4 + 1)];
            dst[0] = v.x > 0.1f; dst[1] = v.y > 0.1f;
            dst[2] = v.z > 0.1f; dst[3] = v.w > 0.1f;
        }
    }
    if (tid < 32) {          // halo top/bottom rows (cols 1..64)
        int q = tid & 15;
        bool top = tid < 16;
        int gr = top ? r0 - 1 : r0 + 64;
        int yy = top ? 0 : 65;
        uint8_t* dst = &lact[yy * 72 + (q * 4 + 1)];
        if ((unsigned)gr < HH) {
            const float4* src = (const float4*)(mask + (size_t)gr * WW + c0);
            float4 v = src[q];
            dst[0] = v.x > 0.1f; dst[1] = v.y > 0.1f;
            dst[2] = v.z > 0.1f; dst[3] = v.w > 0.1f;
        } else {
            dst[0] = 0; dst[1] = 0; dst[2] = 0; dst[3] = 0;
        }
    } else if (tid >= 64 && tid < 64 + 132) {   // halo cols incl corners
        int lane = tid - 64;                    // 0..131
        int side = lane >= 66;                  // 0=left(c0-1), 1=right(c0+64)
        int yy = side ? lane - 66 : lane;       // 0..65
        int gr = r0 - 1 + yy;
        int gc = side ? c0 + 64 : c0 - 1;
        bool a = false;
        if ((unsigned)gr < HH && (unsigned)gc < WW) a = mask[(size_t)gr * WW + gc] > 0.1f;
        lact[yy * 72 + (side ? 65 : 0)] = a ? 1 : 0;
    }
    __syncthreads();
    for (int li = tid; li < TILE; li += LTHREADS) {
        int lr = li >> 6, lc = li & 63;
        int b = (lr + 1) * 72 + (lc + 1);
        int a = lact[b];
        int cnt = lact[b - 73] + lact[b - 72] + lact[b - 71]
                + lact[b - 1]  + a           + lact[b + 1]
                + lact[b + 71] + lact[b + 72] + lact[b + 73];
        lc8[li] = (uint8_t)(a | ((a && cnt >= 4) ? 2 : 0));  // MIN_SAMPLES=4 incl self
        lp[li] = li;
    }
    __syncthreads();
    if (tid < 256) {   // flags -> global, 16B per thread
        int row = tid >> 2, chunk = tid & 3;
        ((uint4*)(flags + (size_t)(r0 + row) * WW + c0))[chunk] =
            ((const uint4*)lc8)[row * 4 + chunk];
    }
    // union dedup (8-conn): W and N unconditional; NW only if !N && !W;
    // NE only if !N && !E (covering unions are unconditional; order-independent)
    for (int li = tid; li < TILE; li += LTHREADS) {
        if (!(lc8[li] & 2)) continue;
        int lr = li >> 6, lc = li & 63;
        bool w = (lc > 0) && (lc8[li - 1] & 2);
        if (w) l_union(lp, li, li - 1);
        if (lr > 0) {
            bool n = (lc8[li - 64] & 2) != 0;
            if (n) {
                l_union(lp, li, li - 64);
            } else {
                if (!w && lc > 0 && (lc8[li - 65] & 2)) l_union(lp, li, li - 65);
                if (lc < 63 && !(lc8[li + 1] & 2) && (lc8[li - 63] & 2))
                    l_union(lp, li, li - 63);
            }
        }
    }
    __syncthreads();
    // write parent for ALL pixels: core -> global root, non-core -> -1
    for (int li = tid; li < TILE; li += LTHREADS) {
        int v = -1;
        if (lc8[li] & 2) {
            int root = li, p;
            while ((p = lp[root]) != root) root = p;   // lp stable after barrier
            v = (r0 + (root >> 6)) * WW + c0 + (root & 63);
        }
        int gi = (r0 + (li >> 6)) * WW + c0 + (li & 63);
        parent[gi] = v;
    }
}

// union only tile-crossing edges (R14-identical)
__global__ __launch_bounds__(THREADS) void k_merge(const uint8_t* __restrict__ flags,
                                                   int* __restrict__ parent) {
    int tile_x = blockIdx.x & 31, tile_y = blockIdx.x >> 5;
    int r0 = tile_y << 6, c0 = tile_x << 6;
    int t = threadIdx.x;
    int lane = t & 63;

    if (t < 64) {                                    // top row, lr=0, lc=t
        int r = r0, c = c0 + t, i = r * WW + c;
        bool selfC = (flags[i] & 2) != 0;
        bool nC = false, nwC = false, neC = false;
        if (selfC && r > 0) {
            nC  = (flags[i - WW] & 2) != 0;
            nwC = (c > 0)      && (flags[i - WW - 1] & 2);
            neC = (c < WW - 1) && (flags[i - WW + 1] & 2);
        }
        int did = 0, ra = -1, rb = -1;
        if (selfC && r > 0 && nC) { ra = uf_find(parent, i); rb = uf_find(parent, i - WW); did = 1; }
        int pra = __shfl_up(ra, 1), prb = __shfl_up(rb, 1), pdid = __shfl_up(did, 1);
        bool head = (lane == 0) || !pdid || pra != ra || prb != rb;
        if (did && head) uf_union(parent, ra, rb);
        if (selfC && r > 0) {
            if (t == 0) {
                if (nwC) uf_union(parent, i, i - WW - 1);          // diag tile
                if (!nC && neC) uf_union(parent, i, i - WW + 1);
            } else if (t == 63) {
                if (!nC && nwC) uf_union(parent, i, i - WW - 1);
                if (neC) {
                    bool eC = (c < WW - 1) && (flags[i + 1] & 2);
                    if (!eC) uf_union(parent, i, i - WW + 1);
                }
            } else if (!nC) {
                if (nwC) uf_union(parent, i, i - WW - 1);
                if (neC) uf_union(parent, i, i - WW + 1);
            }
        }
        if (t == 0 && selfC && c > 0 && (flags[i - 1] & 2))        // corner W edge
            uf_union(parent, i, i - 1);
    } else if (t < 127) {                            // left col, lr=1..63, lc=0
        int lr = t - 63;
        int r = r0 + lr, c = c0, i = r * WW + c;
        bool selfC = (flags[i] & 2) != 0;
        bool wC = false, nwC = false;
        if (selfC && c > 0) {
            wC  = (flags[i - 1] & 2) != 0;
            nwC = (flags[i - WW - 1] & 2) != 0;
        }
        int did = 0, ra = -1, rb = -1;
        if (selfC && wC) { ra = uf_find(parent, i); rb = uf_find(parent, i - 1); did = 1; }
        int pra = __shfl_up(ra, 1), prb = __shfl_up(rb, 1), pdid = __shfl_up(did, 1);
        bool head = (lane == 0) || !pdid || pra != ra || prb != rb;
        if (did && head) uf_union(parent, ra, rb);
        if (selfC && !wC && nwC) uf_union(parent, i, i - WW - 1);
    } else if (t < 190) {                            // right col, lr=1..63, lc=63
        int lr = t - 126;
        int r = r0 + lr, c = c0 + 63, i = r * WW + c;
        bool selfC = (flags[i] & 2) != 0;
        if (selfC && c < WW - 1) {
            bool neC = (flags[i - WW + 1] & 2) != 0;
            bool eC  = (flags[i + 1] & 2) != 0;
            if (neC && !eC) uf_union(parent, i, i - WW + 1);
        }
    }
}

// ---------------- flatten: parent[i] -> final global root ----------------
// After k_merge, chains are strictly index-decreasing (min-root hooking), so
// the walk terminates; concurrent stores only move entries closer to the
// root (benign). After this pass parent[i] IS the final min-label for every
// core pixel, so k_border_stats needs no finds and no resolve hashing.
__global__ __launch_bounds__(THREADS) void k_flatten(int* __restrict__ parent) {
    int i4 = (blockIdx.x * THREADS + threadIdx.x) * 4;
    vi4 v = *((vi4*)(parent + i4));
    vi4 o = v;
    #pragma unroll
    for (int t = 0; t < 4; ++t) {
        int p = v[t];
        if (p >= 0) {
            int q = uf_load(parent, p);
            while (q != p) { p = q; q = uf_load(parent, p); }
            v[t] = p;
        }
    }
    if (v.x != o.x || v.y != o.y || v.z != o.z || v.w != o.w)
        *((vi4*)(parent + i4)) = v;
}

// ---------------- border + stats: parent[] holds FINAL roots ----------------
// Core pixel: lab = parent[i] (direct). Border pixel: lab = min over the 8
// neighbor parent values (>=0 iff core; already final roots). Only the
// run-aggregation hash for sizes/colsum remains in LDS.
__global__ __launch_bounds__(THREADS) void k_border_stats(
        const uint8_t* __restrict__ flags, const int* __restrict__ parent,
        int* __restrict__ labfull, int* __restrict__ sizes,
        unsigned* __restrict__ colsum,
        int* __restrict__ cand, int* __restrict__ counter) {
    __shared__ int s_lab[HSZ];
    __shared__ int s_sz[HSZ];
    __shared__ unsigned s_cs[HSZ];
    for (int t = threadIdx.x; t < HSZ; t += THREADS) {
        s_lab[t] = -1; s_sz[t] = 0; s_cs[t] = 0;
    }
    __syncthreads();

    const int i = blockIdx.x * THREADS + threadIdx.x;
    const int f = flags[i];
    const int r = i >> 11, c = i & (WW - 1);

    int lab = BIGL;
    if (f & 2) {
        lab = parent[i];                         // final root, coalesced
    } else if (f & 1) {                          // active non-core
        const int dr8[8] = {-1,-1,-1, 0,0, 1,1,1};
        const int dc8[8] = {-1, 0, 1,-1,1,-1,0,1};
        int m = BIGL;
        #pragma unroll
        for (int t = 0; t < 8; ++t) {
            int rr = r + dr8[t], cc = c + dc8[t];
            if ((unsigned)rr < HH && (unsigned)cc < WW) {
                int p = parent[rr * WW + cc];    // single load; final root iff >=0
                if (p >= 0 && p < m) m = p;
            }
        }
        lab = m;                                 // BIGL if no core neighbor
    }
    labfull[i] = lab;

    // wave-level run aggregation (WW % 64 == 0: wave never crosses a row)
    int lane = threadIdx.x & 63;
    int labp = __shfl_up(lab, 1);
    bool head = (lane == 0) || (labp != lab);
    unsigned long long hm = __ballot(head);
    if (head && lab < BIGL) {
        unsigned long long rest = (hm >> lane) >> 1;
        int len = rest ? __ffsll((unsigned long long)rest) : (64 - lane);
        unsigned csum = (unsigned)(c * len + len * (len - 1) / 2);
        unsigned slot = (((unsigned)lab * 2654435761u) >> 20) & (HSZ - 1);
        for (;;) {
            int old = atomicCAS(&s_lab[slot], -1, lab);
            if (old == -1 || old == lab) {
                atomicAdd(&s_sz[slot], len);
                atomicAdd(&s_cs[slot], csum);
                break;
            }
            slot = (slot + 1) & (HSZ - 1);
        }
    }
    __syncthreads();
    for (int t = threadIdx.x; t < HSZ; t += THREADS) {
        int lb = s_lab[t];
        if (lb >= 0) {
            int add = s_sz[t];
            int old = atomicAdd(&sizes[lb], add);
            if (old < MINCL && old + add >= MINCL) {   // exactly one block sees this
                int p = atomicAdd(counter, 1);
                cand[p] = lb;
            }
            atomicAdd(&colsum[lb], s_cs[t]);
        }
    }
}

// ---- fused single-kernel top-26 selection (R14-identical, u32 colsum) ----
__device__ __forceinline__ u64 wave_min_u64(u64 m) {
    #pragma unroll
    for (int off = 32; off; off >>= 1) {
        u64 o = __shfl_xor(m, off);
        if (o < m) m = o;
    }
    return m;
}

__global__ __launch_bounds__(THREADS) void k_sel(const int* __restrict__ cand,
                                                 int* __restrict__ counter,   // [0]=n, [1]=done
                                                 const int* __restrict__ sizes,
                                                 const unsigned* __restrict__ colsum,
                                                 unsigned long long* __restrict__ top26g,
                                                 signed char* __restrict__ chan) {
    __shared__ u64 wout[4 * NSLOTS];
    const int tid = threadIdx.x, lane = tid & 63, wv = tid >> 6;
    const int n = counter[0];
    int slice = (n + NB - 1) / NB;
    int j0 = blockIdx.x * slice;
    int j1 = j0 + slice; if (j1 > n) j1 = n;
    int len = j1 - j0; if (len < 0) len = 0;
    int chunk = (len + 3) >> 2;
    int s0 = j0 + wv * chunk;
    int s1 = s0 + chunk; if (s1 > j1) s1 = j1;

    u64 kk[3] = { ~0ull, ~0ull, ~0ull };
    #pragma unroll
    for (int t = 0; t < 3; ++t) {
        int j = s0 + lane + 64 * t;
        if (j < s1) {
            int lab = cand[j];
            float mean = (float)colsum[lab] / (float)sizes[lab];
            kk[t] = ((u64)__float_as_uint(mean) << 32) | (unsigned)lab;
        }
    }
    for (int k = 0; k < NSLOTS; ++k) {
        u64 m = kk[0]; int li = 0;
        if (kk[1] < m) { m = kk[1]; li = 1; }
        if (kk[2] < m) { m = kk[2]; li = 2; }
        u64 mpre = m;
        m = wave_min_u64(m);
        if (mpre == m && m != ~0ull) kk[li] = ~0ull;
        if (lane == 0) wout[wv * NSLOTS + k] = m;
    }
    __syncthreads();
    if (wv == 0) {
        u64 a = (lane < 4 * NSLOTS) ? wout[lane] : ~0ull;
        u64 b = (lane + 64 < 4 * NSLOTS) ? wout[lane + 64] : ~0ull;
        for (int k = 0; k < NSLOTS; ++k) {
            u64 m = a < b ? a : b; int li = a < b ? 0 : 1;
            u64 mpre = m;
            m = wave_min_u64(m);
            if (mpre == m && m != ~0ull) { if (li == 0) a = ~0ull; else b = ~0ull; }
            if (lane == 0) top26g[blockIdx.x * NSLOTS + k] = m;
        }
    }
    __syncthreads();
    __shared__ int lastflag;
    if (tid == 0) {
        __threadfence();
        lastflag = (atomicAdd(&counter[1], 1) == NB - 1);
    }
    __syncthreads();
    if (!lastflag) return;

    u64 mk[13];
    #pragma unroll
    for (int t = 0; t < 13; ++t) {
        int j = wv * 832 + lane + 64 * t;
        mk[t] = __hip_atomic_load(&top26g[j], __ATOMIC_RELAXED, __HIP_MEMORY_SCOPE_AGENT);
    }
    for (int k = 0; k < NSLOTS; ++k) {
        u64 m = mk[0]; int li = 0;
        #pragma unroll
        for (int t = 1; t < 13; ++t) if (mk[t] < m) { m = mk[t]; li = t; }
        u64 mpre = m;
        m = wave_min_u64(m);
        if (mpre == m && m != ~0ull) mk[li] = ~0ull;
        if (lane == 0) wout[wv * NSLOTS + k] = m;
    }
    __syncthreads();
    if (wv == 0) {
        u64 a = (lane < 4 * NSLOTS) ? wout[lane] : ~0ull;
        u64 b = (lane + 64 < 4 * NSLOTS) ? wout[lane + 64] : ~0ull;
        for (int k = 0; k < NSLOTS; ++k) {
            u64 m = a < b ? a : b; int li = a < b ? 0 : 1;
            u64 mpre = m;
            m = wave_min_u64(m);
            if (mpre == m && m != ~0ull) { if (li == 0) a = ~0ull; else b = ~0ull; }
            if (lane == 0 && m != ~0ull)
                chan[(unsigned int)(m & 0xFFFFFFFFull)] = (signed char)k;
        }
    }
}

// one-hot 26xHxW int32 output, non-temporal int4 stores (R14-identical)
__global__ __launch_bounds__(THREADS) void k_output(const int* __restrict__ labfull,
                                                    const signed char* __restrict__ chan,
                                                    int* __restrict__ out) {
    int i4 = (blockIdx.x * THREADS + threadIdx.x) * 4;
    int chv[4];
    #pragma unroll
    for (int t = 0; t < 4; ++t) {
        int lab = labfull[i4 + t];
        chv[t] = (lab < BIGL) ? (int)chan[lab] : -1;
    }
    #pragma unroll
    for (int c = 0; c < NSLOTS; ++c) {
        vi4 v;
        v.x = (chv[0] == c) ? 1 : 0;
        v.y = (chv[1] == c) ? 1 : 0;
        v.z = (chv[2] == c) ? 1 : 0;
        v.w = (chv[3] == c) ? 1 : 0;
        __builtin_nontemporal_store(v, (vi4*)(out + (size_t)c * HWN + i4));
    }
}

extern "C" void kernel_launch(void* const* d_in, const int* in_sizes, int n_in,
                              void* d_out, int out_size, void* d_ws, size_t ws_size,
                              hipStream_t stream) {
    const float* mask = (const float*)d_in[0];
    int* out = (int*)d_out;

    char* w = (char*)d_ws;
    int* parent                 = (int*)(w);                          //  8 MB
    int* labfull                = (int*)(w + (size_t)HWN * 4);        //  8 MB
    int* sizes                  = (int*)(w + (size_t)HWN * 8);        //  8 MB
    unsigned* colsum            = (unsigned*)(w + (size_t)HWN * 12);  //  8 MB (u32)
    uint8_t* flags              = (uint8_t*)(w + (size_t)HWN * 16);   //  2 MB
    signed char* chan           = (signed char*)(w + (size_t)HWN * 17); // 2 MB
    int* cand                   = (int*)(w + (size_t)HWN * 18);       // 280 KB
    int* counter                = (int*)(w + (size_t)HWN * 18 + MAXCAND * 4);  // [0]=n,[1]=done
    unsigned long long* top26g  = (unsigned long long*)(w + (size_t)HWN * 18 + MAXCAND * 4 + 256);

    // no memsets: k_local zeros sizes/colsum/chan/counter/done
    const int blocks = HWN / THREADS;   // 8192
    k_local       <<<NTILES, LTHREADS, 0, stream>>>(mask, flags, parent,
                                                    sizes, colsum, chan, counter);
    k_merge       <<<NTILES, THREADS, 0, stream>>>(flags, parent);
    k_flatten     <<<HWN / (4 * THREADS), THREADS, 0, stream>>>(parent);
    k_border_stats<<<blocks, THREADS, 0, stream>>>(flags, parent, labfull, sizes, colsum,
                                                   cand, counter);
    k_sel         <<<NB, THREADS, 0, stream>>>(cand, counter, sizes, colsum, top26g, chan);
    k_output      <<<HWN / (4 * THREADS), THREADS, 0, stream>>>(labfull, chan, out);
}

// Round 2
// 373.886 us; speedup vs baseline: 1.0420x; 1.0140x over previous
//
#include <hip/hip_runtime.h>
#include <stdint.h>

#define HH 1024
#define WW 2048
#define HWN (HH*WW)          // 2097152
#define BIGL HWN             // 'no cluster' sentinel
#define NSLOTS 26
#define MINCL 30
#define THREADS 256
#define LTHREADS 512         // k_local block size (8 waves)
#define MAXCAND 70000        // >= HWN/30 + 1
#define HSZ 512              // run-aggregation hash entries (256-pixel strip)
#define TILE 4096            // 64x64 tile
#define NTILES 512           // (1024/64)*(2048/64)
#define NB 128               // selection blocks

typedef int vi4 __attribute__((ext_vector_type(4)));
typedef unsigned long long u64;

// ---------------- global union-find (lock-free, min-root) ----------------
__device__ __forceinline__ int uf_load(int* p, int i) {
    return __hip_atomic_load(&p[i], __ATOMIC_RELAXED, __HIP_MEMORY_SCOPE_AGENT);
}
__device__ __forceinline__ void uf_store(int* p, int i, int v) {
    __hip_atomic_store(&p[i], v, __ATOMIC_RELAXED, __HIP_MEMORY_SCOPE_AGENT);
}
__device__ int uf_find(int* parent, int x) {
    int p = uf_load(parent, x);
    while (p != x) {
        int gp = uf_load(parent, p);
        if (gp != p) uf_store(parent, x, gp);   // path halving (benign race)
        x = p; p = gp;
    }
    return p;
}
__device__ void uf_union(int* parent, int a, int b) {
    int ra = uf_find(parent, a);
    int rb = uf_find(parent, b);
    while (ra != rb) {
        if (ra > rb) { int t = ra; ra = rb; rb = t; }   // hook larger under smaller
        int old = atomicCAS(&parent[rb], rb, ra);
        if (old == rb) return;
        rb = uf_find(parent, old);
        ra = uf_find(parent, ra);
    }
}

// ---------------- LDS union-find (block-local, min-root) ----------------
__device__ __forceinline__ int l_load(int* p, int i) {
    return __hip_atomic_load(&p[i], __ATOMIC_RELAXED, __HIP_MEMORY_SCOPE_WORKGROUP);
}
__device__ __forceinline__ void l_store(int* p, int i, int v) {
    __hip_atomic_store(&p[i], v, __ATOMIC_RELAXED, __HIP_MEMORY_SCOPE_WORKGROUP);
}
__device__ int l_find(int* lp, int x) {
    int p = l_load(lp, x);
    while (p != x) {
        int gp = l_load(lp, p);
        if (gp != p) l_store(lp, x, gp);
        x = p; p = gp;
    }
    return p;
}
__device__ void l_union(int* lp, int a, int b) {
    int ra = l_find(lp, a);
    int rb = l_find(lp, b);
    while (ra != rb) {
        if (ra > rb) { int t = ra; ra = rb; rb = t; }
        int old = atomicCAS(&lp[rb], rb, ra);
        if (old == rb) return;
        rb = l_find(lp, old);
        ra = l_find(lp, ra);
    }
}

// ---------------- fused init + per-tile CC + ws zeroing ----------------
// parent[] is self-describing: -1 for non-core, global tile-root for core.
// Wave geometry: LTHREADS=512 -> each wave covers exactly one 64-px tile row
// per pass. Horizontal runs are resolved in registers via ballot: lp[] is
// initialized to the run HEAD, eliminating all W unions; N/NW/NE unions
// collapse to one l_union per (run, north-run) overlap segment.
__global__ __launch_bounds__(LTHREADS) void k_local(const float* __restrict__ mask,
                                                    uint8_t* __restrict__ flags,
                                                    int* __restrict__ parent,
                                                    int* __restrict__ sizes,
                                                    unsigned* __restrict__ colsum,
                                                    signed char* __restrict__ chan,
                                                    int* __restrict__ counter) {
    __shared__ uint8_t lact[66 * 72];   // halo active map, row stride 72
    __shared__ uint8_t lc8[TILE];
    __shared__ int lp[TILE];
    const int tid = threadIdx.x;
    const int lane = tid & 63;
    int tile_x = blockIdx.x & 31, tile_y = blockIdx.x >> 5;
    int r0 = tile_y << 6, c0 = tile_x << 6;

    {   // zero this block's 1/512 slice of sizes/colsum/chan (+counter/done once)
        int base = blockIdx.x * (HWN / NTILES);      // 4096 elements
        vi4* sz4 = (vi4*)(sizes + base);
        vi4* cs4 = (vi4*)(colsum + base);
        for (int t = tid; t < 1024; t += LTHREADS) sz4[t] = (vi4)0;
        for (int t = tid; t < 1024; t += LTHREADS) cs4[t] = (vi4)0;   // u32 colsum
        vi4* ch4 = (vi4*)(chan + base);
        for (int t = tid; t < 256; t += LTHREADS) ch4[t] = (vi4)(-1);
        if (blockIdx.x == 0 && tid == 0) { counter[0] = 0; counter[1] = 0; }
    }

    {   // body rows: 64 rows x 16 float4, coalesced; 512 threads -> 2 passes
        int lr = tid >> 4, q = tid & 15;
        #pragma unroll
        for (int pass = 0; pass < 2; ++pass) {
            int rr = lr + pass * 32;
            const float4* src = (const float4*)(mask + (size_t)(r0 + rr) * WW + c0);
            float4 v = src[q];
            uint8_t* dst = &lact[(rr + 1) * 72 + (q * 4 + 1)];
            dst[0] = v.x > 0.1f; dst[1] = v.y > 0.1f;
            dst[2] = v.z > 0.1f; dst[3] = v.w > 0.1f;
        }
    }
    if (tid < 32) {          // halo top/bottom rows (cols 1..64)
        int q = tid & 15;
        bool top = tid < 16;
        int gr = top ? r0 - 1 : r0 + 64;
        int yy = top ? 0 : 65;
        uint8_t* dst = &lact[yy * 72 + (q * 4 + 1)];
        if ((unsigned)gr < HH) {
            const float4* src = (const float4*)(mask + (size_t)gr * WW + c0);
            float4 v = src[q];
            dst[0] = v.x > 0.1f; dst[1] = v.y > 0.1f;
            dst[2] = v.z > 0.1f; dst[3] = v.w > 0.1f;
        } else {
            dst[0] = 0; dst[1] = 0; dst[2] = 0; dst[3] = 0;
        }
    } else if (tid >= 64 && tid < 64 + 132) {   // halo cols incl corners
        int lane2 = tid - 64;                   // 0..131
        int side = lane2 >= 66;                 // 0=left(c0-1), 1=right(c0+64)
        int yy = side ? lane2 - 66 : lane2;     // 0..65
        int gr = r0 - 1 + yy;
        int gc = side ? c0 + 64 : c0 - 1;
        bool a = false;
        if ((unsigned)gr < HH && (unsigned)gc < WW) a = mask[(size_t)gr * WW + gc] > 0.1f;
        lact[yy * 72 + (side ? 65 : 0)] = a ? 1 : 0;
    }
    __syncthreads();
    // core flags + run-head lp init (one wave == one tile row per pass)
    #pragma unroll
    for (int pass = 0; pass < 8; ++pass) {
        int li = tid + pass * LTHREADS;
        int lr = li >> 6, lc = li & 63;
        int b = (lr + 1) * 72 + (lc + 1);
        int a = lact[b];
        int cnt = lact[b - 73] + lact[b - 72] + lact[b - 71]
                + lact[b - 1]  + a           + lact[b + 1]
                + lact[b + 71] + lact[b + 72] + lact[b + 73];
        bool core = a && (cnt >= 4);                    // MIN_SAMPLES=4 incl self
        lc8[li] = (uint8_t)(a | (core ? 2 : 0));
        u64 bc = __ballot(core);
        u64 st = bc & ~(bc << 1);                       // run starts
        int hl = 63 - __clzll(st & ((2ull << lane) - 1));  // valid iff core
        lp[li] = core ? ((li & ~63) | hl) : li;
    }
    __syncthreads();
    if (tid < 256) {   // flags -> global, 16B per thread
        int row = tid >> 2, chunk = tid & 3;
        ((uint4*)(flags + (size_t)(r0 + row) * WW + c0))[chunk] =
            ((const uint4*)lc8)[row * 4 + chunk];
    }
    // vertical/diagonal unions between run heads, one per overlap segment.
    // Covering (8-conn): N per (run,nrun) segment; NW only if !N && !W;
    // NE only if !N && !E (W/E covered by run init, their N-edges cover diags).
    #pragma unroll
    for (int pass = 0; pass < 8; ++pass) {
        int li = tid + pass * LTHREADS;
        int row = li >> 6;
        if (row == 0) continue;                         // wave-uniform
        bool core  = (lc8[li] & 2) != 0;
        bool ncore = (lc8[li - 64] & 2) != 0;
        u64 bc = __ballot(core);
        u64 nb = __ballot(ncore);
        if (!bc || !nb) continue;                       // wave-uniform
        u64 sst = bc & ~(bc << 1);
        u64 nst = nb & ~(nb << 1);
        if (core) {
            int myhead = (li & ~63) | (63 - __clzll(sst & ((2ull << lane) - 1)));
            int nrow0 = (li - 64) & ~63;
            if (ncore) {
                bool prevpair = lane > 0 && ((bc >> (lane - 1)) & 1)
                                         && ((nb >> (lane - 1)) & 1);
                bool newseg = !prevpair || ((sst >> lane) & 1) || ((nst >> lane) & 1);
                if (newseg) {
                    int nhead = nrow0 | (63 - __clzll(nst & ((2ull << lane) - 1)));
                    l_union(lp, myhead, nhead);
                }
            } else {
                bool wcore  = lane > 0 && ((bc >> (lane - 1)) & 1);
                bool nwcore = lane > 0 && ((nb >> (lane - 1)) & 1);
                if (!wcore && nwcore) {
                    int nhead = nrow0 | (63 - __clzll(nst & ((1ull << lane) - 1)));
                    l_union(lp, myhead, nhead);
                }
                bool ecore  = lane < 63 && ((bc >> (lane + 1)) & 1);
                bool necore = lane < 63 && ((nb >> (lane + 1)) & 1);
                if (!ecore && necore) {
                    int nhead = nrow0 | (63 - __clzll(nst & ((4ull << lane) - 1)));
                    l_union(lp, myhead, nhead);
                }
            }
        }
    }
    __syncthreads();
    // write parent for ALL pixels: core -> global root, non-core -> -1
    for (int li = tid; li < TILE; li += LTHREADS) {
        int v = -1;
        if (lc8[li] & 2) {
            int root = li, p;
            while ((p = lp[root]) != root) root = p;   // lp stable after barrier
            v = (r0 + (root >> 6)) * WW + c0 + (root & 63);
        }
        int gi = (r0 + (li >> 6)) * WW + c0 + (li & 63);
        parent[gi] = v;
    }
}

// union only tile-crossing edges (R14-identical)
__global__ __launch_bounds__(THREADS) void k_merge(const uint8_t* __restrict__ flags,
                                                   int* __restrict__ parent) {
    int tile_x = blockIdx.x & 31, tile_y = blockIdx.x >> 5;
    int r0 = tile_y << 6, c0 = tile_x << 6;
    int t = threadIdx.x;
    int lane = t & 63;

    if (t < 64) {                                    // top row, lr=0, lc=t
        int r = r0, c = c0 + t, i = r * WW + c;
        bool selfC = (flags[i] & 2) != 0;
        bool nC = false, nwC = false, neC = false;
        if (selfC && r > 0) {
            nC  = (flags[i - WW] & 2) != 0;
            nwC = (c > 0)      && (flags[i - WW - 1] & 2);
            neC = (c < WW - 1) && (flags[i - WW + 1] & 2);
        }
        int did = 0, ra = -1, rb = -1;
        if (selfC && r > 0 && nC) { ra = uf_find(parent, i); rb = uf_find(parent, i - WW); did = 1; }
        int pra = __shfl_up(ra, 1), prb = __shfl_up(rb, 1), pdid = __shfl_up(did, 1);
        bool head = (lane == 0) || !pdid || pra != ra || prb != rb;
        if (did && head) uf_union(parent, ra, rb);
        if (selfC && r > 0) {
            if (t == 0) {
                if (nwC) uf_union(parent, i, i - WW - 1);          // diag tile
                if (!nC && neC) uf_union(parent, i, i - WW + 1);
            } else if (t == 63) {
                if (!nC && nwC) uf_union(parent, i, i - WW - 1);
                if (neC) {
                    bool eC = (c < WW - 1) && (flags[i + 1] & 2);
                    if (!eC) uf_union(parent, i, i - WW + 1);
                }
            } else if (!nC) {
                if (nwC) uf_union(parent, i, i - WW - 1);
                if (neC) uf_union(parent, i, i - WW + 1);
            }
        }
        if (t == 0 && selfC && c > 0 && (flags[i - 1] & 2))        // corner W edge
            uf_union(parent, i, i - 1);
    } else if (t < 127) {                            // left col, lr=1..63, lc=0
        int lr = t - 63;
        int r = r0 + lr, c = c0, i = r * WW + c;
        bool selfC = (flags[i] & 2) != 0;
        bool wC = false, nwC = false;
        if (selfC && c > 0) {
            wC  = (flags[i - 1] & 2) != 0;
            nwC = (flags[i - WW - 1] & 2) != 0;
        }
        int did = 0, ra = -1, rb = -1;
        if (selfC && wC) { ra = uf_find(parent, i); rb = uf_find(parent, i - 1); did = 1; }
        int pra = __shfl_up(ra, 1), prb = __shfl_up(rb, 1), pdid = __shfl_up(did, 1);
        bool head = (lane == 0) || !pdid || pra != ra || prb != rb;
        if (did && head) uf_union(parent, ra, rb);
        if (selfC && !wC && nwC) uf_union(parent, i, i - WW - 1);
    } else if (t < 190) {                            // right col, lr=1..63, lc=63
        int lr = t - 126;
        int r = r0 + lr, c = c0 + 63, i = r * WW + c;
        bool selfC = (flags[i] & 2) != 0;
        if (selfC && c < WW - 1) {
            bool neC = (flags[i - WW + 1] & 2) != 0;
            bool eC  = (flags[i + 1] & 2) != 0;
            if (neC && !eC) uf_union(parent, i, i - WW + 1);
        }
    }
}

// ---------------- flatten: parent[i] -> final global root ----------------
__global__ __launch_bounds__(THREADS) void k_flatten(int* __restrict__ parent) {
    int i4 = (blockIdx.x * THREADS + threadIdx.x) * 4;
    vi4 v = *((vi4*)(parent + i4));
    vi4 o = v;
    #pragma unroll
    for (int t = 0; t < 4; ++t) {
        int p = v[t];
        if (p >= 0) {
            int q = uf_load(parent, p);
            while (q != p) { p = q; q = uf_load(parent, p); }
            v[t] = p;
        }
    }
    if (v.x != o.x || v.y != o.y || v.z != o.z || v.w != o.w)
        *((vi4*)(parent + i4)) = v;
}

// ---------------- border + stats: parent[] holds FINAL roots ----------------
__global__ __launch_bounds__(THREADS) void k_border_stats(
        const uint8_t* __restrict__ flags, const int* __restrict__ parent,
        int* __restrict__ labfull, int* __restrict__ sizes,
        unsigned* __restrict__ colsum,
        int* __restrict__ cand, int* __restrict__ counter) {
    __shared__ int s_lab[HSZ];
    __shared__ int s_sz[HSZ];
    __shared__ unsigned s_cs[HSZ];
    for (int t = threadIdx.x; t < HSZ; t += THREADS) {
        s_lab[t] = -1; s_sz[t] = 0; s_cs[t] = 0;
    }
    __syncthreads();

    const int i = blockIdx.x * THREADS + threadIdx.x;
    const int f = flags[i];
    const int r = i >> 11, c = i & (WW - 1);

    int lab = BIGL;
    if (f & 2) {
        lab = parent[i];                         // final root, coalesced
    } else if (f & 1) {                          // active non-core
        const int dr8[8] = {-1,-1,-1, 0,0, 1,1,1};
        const int dc8[8] = {-1, 0, 1,-1,1,-1,0,1};
        int m = BIGL;
        #pragma unroll
        for (int t = 0; t < 8; ++t) {
            int rr = r + dr8[t], cc = c + dc8[t];
            if ((unsigned)rr < HH && (unsigned)cc < WW) {
                int p = parent[rr * WW + cc];    // single load; final root iff >=0
                if (p >= 0 && p < m) m = p;
            }
        }
        lab = m;                                 // BIGL if no core neighbor
    }
    labfull[i] = lab;

    // wave-level run aggregation (WW % 64 == 0: wave never crosses a row)
    int lane = threadIdx.x & 63;
    int labp = __shfl_up(lab, 1);
    bool head = (lane == 0) || (labp != lab);
    unsigned long long hm = __ballot(head);
    if (head && lab < BIGL) {
        unsigned long long rest = (hm >> lane) >> 1;
        int len = rest ? __ffsll((unsigned long long)rest) : (64 - lane);
        unsigned csum = (unsigned)(c * len + len * (len - 1) / 2);
        unsigned slot = (((unsigned)lab * 2654435761u) >> 20) & (HSZ - 1);
        for (;;) {
            int old = atomicCAS(&s_lab[slot], -1, lab);
            if (old == -1 || old == lab) {
                atomicAdd(&s_sz[slot], len);
                atomicAdd(&s_cs[slot], csum);
                break;
            }
            slot = (slot + 1) & (HSZ - 1);
        }
    }
    __syncthreads();
    for (int t = threadIdx.x; t < HSZ; t += THREADS) {
        int lb = s_lab[t];
        if (lb >= 0) {
            int add = s_sz[t];
            int old = atomicAdd(&sizes[lb], add);
            if (old < MINCL && old + add >= MINCL) {   // exactly one block sees this
                int p = atomicAdd(counter, 1);
                cand[p] = lb;
            }
            atomicAdd(&colsum[lb], s_cs[t]);
        }
    }
}

// ---- fused single-kernel top-26 selection (u32 colsum) ----
__device__ __forceinline__ u64 wave_min_u64(u64 m) {
    #pragma unroll
    for (int off = 32; off; off >>= 1) {
        u64 o = __shfl_xor(m, off);
        if (o < m) m = o;
    }
    return m;
}

__global__ __launch_bounds__(THREADS) void k_sel(const int* __restrict__ cand,
                                                 int* __restrict__ counter,   // [0]=n, [1]=done
                                                 const int* __restrict__ sizes,
                                                 const unsigned* __restrict__ colsum,
                                                 unsigned long long* __restrict__ top26g,
                                                 signed char* __restrict__ chan) {
    __shared__ u64 wout[4 * NSLOTS];
    const int tid = threadIdx.x, lane = tid & 63, wv = tid >> 6;
    const int n = counter[0];
    int slice = (n + NB - 1) / NB;
    int j0 = blockIdx.x * slice;
    int j1 = j0 + slice; if (j1 > n) j1 = n;
    int len = j1 - j0; if (len < 0) len = 0;
    int chunk = (len + 3) >> 2;
    int s0 = j0 + wv * chunk;
    int s1 = s0 + chunk; if (s1 > j1) s1 = j1;

    u64 kk[3] = { ~0ull, ~0ull, ~0ull };
    #pragma unroll
    for (int t = 0; t < 3; ++t) {
        int j = s0 + lane + 64 * t;
        if (j < s1) {
            int lab = cand[j];
            float mean = (float)colsum[lab] / (float)sizes[lab];
            kk[t] = ((u64)__float_as_uint(mean) << 32) | (unsigned)lab;
        }
    }
    for (int k = 0; k < NSLOTS; ++k) {
        u64 m = kk[0]; int li = 0;
        if (kk[1] < m) { m = kk[1]; li = 1; }
        if (kk[2] < m) { m = kk[2]; li = 2; }
        u64 mpre = m;
        m = wave_min_u64(m);
        if (mpre == m && m != ~0ull) kk[li] = ~0ull;
        if (lane == 0) wout[wv * NSLOTS + k] = m;
    }
    __syncthreads();
    if (wv == 0) {
        u64 a = (lane < 4 * NSLOTS) ? wout[lane] : ~0ull;
        u64 b = (lane + 64 < 4 * NSLOTS) ? wout[lane + 64] : ~0ull;
        for (int k = 0; k < NSLOTS; ++k) {
            u64 m = a < b ? a : b; int li = a < b ? 0 : 1;
            u64 mpre = m;
            m = wave_min_u64(m);
            if (mpre == m && m != ~0ull) { if (li == 0) a = ~0ull; else b = ~0ull; }
            if (lane == 0) top26g[blockIdx.x * NSLOTS + k] = m;
        }
    }
    __syncthreads();
    __shared__ int lastflag;
    if (tid == 0) {
        __threadfence();
        lastflag = (atomicAdd(&counter[1], 1) == NB - 1);
    }
    __syncthreads();
    if (!lastflag) return;

    u64 mk[13];
    #pragma unroll
    for (int t = 0; t < 13; ++t) {
        int j = wv * 832 + lane + 64 * t;
        mk[t] = __hip_atomic_load(&top26g[j], __ATOMIC_RELAXED, __HIP_MEMORY_SCOPE_AGENT);
    }
    for (int k = 0; k < NSLOTS; ++k) {
        u64 m = mk[0]; int li = 0;
        #pragma unroll
        for (int t = 1; t < 13; ++t) if (mk[t] < m) { m = mk[t]; li = t; }
        u64 mpre = m;
        m = wave_min_u64(m);
        if (mpre == m && m != ~0ull) mk[li] = ~0ull;
        if (lane == 0) wout[wv * NSLOTS + k] = m;
    }
    __syncthreads();
    if (wv == 0) {
        u64 a = (lane < 4 * NSLOTS) ? wout[lane] : ~0ull;
        u64 b = (lane + 64 < 4 * NSLOTS) ? wout[lane + 64] : ~0ull;
        for (int k = 0; k < NSLOTS; ++k) {
            u64 m = a < b ? a : b; int li = a < b ? 0 : 1;
            u64 mpre = m;
            m = wave_min_u64(m);
            if (mpre == m && m != ~0ull) { if (li == 0) a = ~0ull; else b = ~0ull; }
            if (lane == 0 && m != ~0ull)
                chan[(unsigned int)(m & 0xFFFFFFFFull)] = (signed char)k;
        }
    }
}

// one-hot 26xHxW int32 output, non-temporal int4 stores
__global__ __launch_bounds__(THREADS) void k_output(const int* __restrict__ labfull,
                                                    const signed char* __restrict__ chan,
                                                    int* __restrict__ out) {
    int i4 = (blockIdx.x * THREADS + threadIdx.x) * 4;
    int chv[4];
    #pragma unroll
    for (int t = 0; t < 4; ++t) {
        int lab = labfull[i4 + t];
        chv[t] = (lab < BIGL) ? (int)chan[lab] : -1;
    }
    #pragma unroll
    for (int c = 0; c < NSLOTS; ++c) {
        vi4 v;
        v.x = (chv[0] == c) ? 1 : 0;
        v.y = (chv[1] == c) ? 1 : 0;
        v.z = (chv[2] == c) ? 1 : 0;
        v.w = (chv[3] == c) ? 1 : 0;
        __builtin_nontemporal_store(v, (vi4*)(out + (size_t)c * HWN + i4));
    }
}

extern "C" void kernel_launch(void* const* d_in, const int* in_sizes, int n_in,
                              void* d_out, int out_size, void* d_ws, size_t ws_size,
                              hipStream_t stream) {
    const float* mask = (const float*)d_in[0];
    int* out = (int*)d_out;

    char* w = (char*)d_ws;
    int* parent                 = (int*)(w);                          //  8 MB
    int* labfull                = (int*)(w + (size_t)HWN * 4);        //  8 MB
    int* sizes                  = (int*)(w + (size_t)HWN * 8);        //  8 MB
    unsigned* colsum            = (unsigned*)(w + (size_t)HWN * 12);  //  8 MB (u32)
    uint8_t* flags              = (uint8_t*)(w + (size_t)HWN * 16);   //  2 MB
    signed char* chan           = (signed char*)(w + (size_t)HWN * 17); // 2 MB
    int* cand                   = (int*)(w + (size_t)HWN * 18);       // 280 KB
    int* counter                = (int*)(w + (size_t)HWN * 18 + MAXCAND * 4);  // [0]=n,[1]=done
    unsigned long long* top26g  = (unsigned long long*)(w + (size_t)HWN * 18 + MAXCAND * 4 + 256);

    // no memsets: k_local zeros sizes/colsum/chan/counter/done
    const int blocks = HWN / THREADS;   // 8192
    k_local       <<<NTILES, LTHREADS, 0, stream>>>(mask, flags, parent,
                                                    sizes, colsum, chan, counter);
    k_merge       <<<NTILES, THREADS, 0, stream>>>(flags, parent);
    k_flatten     <<<HWN / (4 * THREADS), THREADS, 0, stream>>>(parent);
    k_border_stats<<<blocks, THREADS, 0, stream>>>(flags, parent, labfull, sizes, colsum,
                                                   cand, counter);
    k_sel         <<<NB, THREADS, 0, stream>>>(cand, counter, sizes, colsum, top26g, chan);
    k_output      <<<HWN / (4 * THREADS), THREADS, 0, stream>>>(labfull, chan, out);
}